// Round 2
// baseline (86.630 us; speedup 1.0000x reference)
//
#include <hip/hip_runtime.h>
#include <hip/hip_bf16.h>

// Problem constants (from reference): B=128, A=128, D=8, F=256, BF=16 (bonds unused)
#define NB 128
#define NA 128
#define ND 8
#define NF 256
#define NF4 (NF / 4)   // 64 float4 per feature row

typedef float v4f __attribute__((ext_vector_type(4)));

// One wave (64 lanes) per atom: lane i owns float4 i of the 256-float row.
// Block = 256 threads = 4 atoms. Edges are wave-uniform -> scalar (s_load) path.
__global__ __launch_bounds__(256) void NeuralGraphPool_52072183497147_kernel(
        const v4f* __restrict__ atoms,   // (B, A, F) as float4 rows
        const int* __restrict__ edges,   // (B, A, D)
        v4f*       __restrict__ out)     // (B, A, F)
{
    const int tid  = threadIdx.x;
    const int lane = tid & 63;                        // float4 index in row
    const int aIdx = (blockIdx.x << 2) + (tid >> 6);  // global atom index b*A + a
    // aIdx is uniform across the wave: pin it to an SGPR so the edge loads
    // become scalar loads (s_load_dwordx8) instead of 8 per-lane VMEM loads.
    const int uA   = __builtin_amdgcn_readfirstlane(aIdx);
    const int b    = uA >> 7;                         // / NA
    const int base = uA * NF4;

    // self feature
    v4f v = atoms[base + lane];

    const int* e = edges + uA * ND;
    int ev[ND];
    #pragma unroll
    for (int d = 0; d < ND; ++d) ev[d] = e[d];        // uniform ptr -> scalar loads

    int deg = 0;
    #pragma unroll
    for (int d = 0; d < ND; ++d) {
        const bool ok = (ev[d] >= 0);
        deg += ok ? 1 : 0;
        // padding edge: reference gathers the zero pad-row -> contributes 0.0
        // to the max. Branch-free: load a valid row (row 0) and scale by 0.
        const int row = ok ? ev[d] : 0;
        const float m = ok ? 1.0f : 0.0f;
        v4f n = atoms[((b << 7) + row) * NF4 + lane];
        n = n * m;
        v.x = fmaxf(v.x, n.x);
        v.y = fmaxf(v.y, n.y);
        v.z = fmaxf(v.z, n.z);
        v.w = fmaxf(v.w, n.w);
    }

    if (deg == 0) {
        v = (v4f){0.0f, 0.0f, 0.0f, 0.0f};
    }
    // out is write-only and never re-read: bypass L2 (keep it for the gathers)
    __builtin_nontemporal_store(v, &out[base + lane]);
}

extern "C" void kernel_launch(void* const* d_in, const int* in_sizes, int n_in,
                              void* d_out, int out_size, void* d_ws, size_t ws_size,
                              hipStream_t stream) {
    const v4f* atoms = (const v4f*)d_in[0];
    // d_in[1] = bonds (B,A,D,BF) float32 — unused by the reference.
    const int* edges = (const int*)d_in[2];
    v4f*       out   = (v4f*)d_out;

    const int nAtoms = NB * NA;            // 16384
    dim3 grid(nAtoms / 4);                 // 4096 blocks
    dim3 block(256);
    NeuralGraphPool_52072183497147_kernel<<<grid, block, 0, stream>>>(atoms, edges, out);
}